// Round 15
// baseline (680.085 us; speedup 1.0000x reference)
//
#include <hip/hip_runtime.h>
#include <cstdint>
#include <cstddef>

#define S_LEN 4096
#define DVEC  1024
#define DH    256

typedef __attribute__((ext_vector_type(8))) short short8;
typedef __attribute__((ext_vector_type(4))) float f32x4;
typedef __attribute__((ext_vector_type(4))) unsigned short ushort4v;

__device__ __forceinline__ unsigned short f2bf(float f) {
  unsigned u = __builtin_bit_cast(unsigned, f);
  u += 0x7FFFu + ((u >> 16) & 1u);          // round-to-nearest-even
  return (unsigned short)(u >> 16);
}

__device__ __forceinline__ void gl2lds16(const void* g, void* lds) {
  __builtin_amdgcn_global_load_lds(
      (const __attribute__((address_space(1))) unsigned int*)g,
      (__attribute__((address_space(3))) unsigned int*)lds, 16, 0, 0);
}

__device__ __forceinline__ void cbar() { asm volatile("" ::: "memory"); }

// BAR1 (r13-verbatim): LDS visibility only (P writes / QK reads). All
// register loads (V, mask) are auto-guarded by compiler dep-waits.
__device__ __forceinline__ void bar_lgkm() {
  asm volatile("s_waitcnt lgkmcnt(0)" ::: "memory");
  __builtin_amdgcn_s_barrier();
  asm volatile("" ::: "memory");
}
// BAR2: additionally drains stageK's gl2lds (the only op with no register
// consumer). >=12 reg-loads are issued after stageK (cbar-fenced), so
// vmcnt(8) strictly covers it; worst case also waits on 4 old mask loads.
__device__ __forceinline__ void bar_vm8() {
  asm volatile("s_waitcnt vmcnt(8) lgkmcnt(0)" ::: "memory");
  __builtin_amdgcn_s_barrier();
  asm volatile("" ::: "memory");
}
__device__ __forceinline__ void bar_vm0() {
  asm volatile("s_waitcnt vmcnt(0) lgkmcnt(0)" ::: "memory");
  __builtin_amdgcn_s_barrier();
  asm volatile("" ::: "memory");
}

// ---------------------------------------------------------------------------
// Kernel 1: weights f32 -> bf16 (wq pre-scaled by 1/sqrt(DH)=1/16).
// ---------------------------------------------------------------------------
__global__ void wcvt_kernel(const float* __restrict__ wq,
                            const float* __restrict__ wk,
                            const float* __restrict__ wv,
                            unsigned short* __restrict__ wbf) {
  int t   = blockIdx.x * 256 + threadIdx.x;
  int idx = t * 4;
  int m   = idx >> 18;
  int off = idx & 262143;
  const float* src = (m == 0) ? wq : (m == 1) ? wk : wv;
  float scale = (m == 0) ? 0.0625f : 1.0f;
  f32x4 v = *(const f32x4*)(src + off);
  ushort4v o;
  o.x = f2bf(v.x * scale);
  o.y = f2bf(v.y * scale);
  o.z = f2bf(v.z * scale);
  o.w = f2bf(v.w * scale);
  *(ushort4v*)(wbf + idx) = o;
}

// ---------------------------------------------------------------------------
// Kernel 2: projection GEMM (unchanged). C = x * W^T + b -> bf16; z==2 -> V^T.
// ---------------------------------------------------------------------------
__global__ void proj_kernel(const float* __restrict__ xq,
                            const float* __restrict__ xk,
                            const float* __restrict__ xv,
                            const unsigned short* __restrict__ wbf,
                            const float* __restrict__ bq,
                            const float* __restrict__ bk,
                            const float* __restrict__ bv,
                            unsigned short* __restrict__ qbf,
                            unsigned short* __restrict__ kbf,
                            unsigned short* __restrict__ vtbf) {
  const int tid  = threadIdx.x;
  const int lane = tid & 63;
  const int w    = tid >> 6;
  const int z    = blockIdx.z;
  const int m0   = blockIdx.x * 64;

  const float* x = (z == 0) ? xq : (z == 1) ? xk : xv;
  const unsigned short* wz = wbf + (size_t)z * (DH * DVEC);
  const float* bias = (z == 0) ? bq : (z == 1) ? bk : bv;
  const float bscale = (z == 0) ? 0.0625f : 1.0f;

  __shared__ float At[2][64 * 32];

  f32x4 zero = {0.f, 0.f, 0.f, 0.f};
  f32x4 acc[4][4];
#pragma unroll
  for (int i = 0; i < 4; ++i)
#pragma unroll
    for (int j = 0; j < 4; ++j) acc[i][j] = zero;

  auto stage = [&](int kt, int buf) {
    char* dstb = (char*)&At[buf][0] + w * 2048;
#pragma unroll
    for (int i = 0; i < 2; ++i) {
      int lin  = w * 2048 + i * 1024 + lane * 16;
      int row  = lin >> 7;
      int scol = (lin ^ ((row & 7) << 4)) & 127;
      gl2lds16((const char*)x + ((size_t)(m0 + row) * DVEC + kt * 32) * 4 + scol,
               dstb + i * 1024);
    }
  };

  stage(0, 0);
  __syncthreads();

  for (int kt = 0; kt < 32; ++kt) {
    const int buf = kt & 1;
    if (kt + 1 < 32) stage(kt + 1, buf ^ 1);

    short8 bfr[4];
#pragma unroll
    for (int cf = 0; cf < 4; ++cf) {
      int h = w * 64 + cf * 16 + (lane & 15);
      int d = kt * 32 + (lane >> 4) * 8;
      bfr[cf] = *(const short8*)(wz + (size_t)h * DVEC + d);
    }
    const char* ab = (const char*)&At[buf][0];
#pragma unroll
    for (int rf = 0; rf < 4; ++rf) {
      int row = rf * 16 + (lane & 15);
      int c0  = row * 128 + (lane >> 4) * 32;
      int sw  = (row & 7) << 4;
      f32x4 v0 = *(const f32x4*)(ab + (c0 ^ sw));
      f32x4 v1 = *(const f32x4*)(ab + ((c0 + 16) ^ sw));
      short8 af;
      af[0] = (short)f2bf(v0.x); af[1] = (short)f2bf(v0.y);
      af[2] = (short)f2bf(v0.z); af[3] = (short)f2bf(v0.w);
      af[4] = (short)f2bf(v1.x); af[5] = (short)f2bf(v1.y);
      af[6] = (short)f2bf(v1.z); af[7] = (short)f2bf(v1.w);
#pragma unroll
      for (int cf = 0; cf < 4; ++cf)
        acc[rf][cf] = __builtin_amdgcn_mfma_f32_16x16x32_bf16(af, bfr[cf], acc[rf][cf], 0, 0, 0);
    }
    __syncthreads();
  }

  float bvv[4];
#pragma unroll
  for (int cf = 0; cf < 4; ++cf)
    bvv[cf] = bias[w * 64 + cf * 16 + (lane & 15)] * bscale;

  if (z < 2) {
    unsigned short* o = (z == 0) ? qbf : kbf;
#pragma unroll
    for (int rf = 0; rf < 4; ++rf)
#pragma unroll
      for (int cf = 0; cf < 4; ++cf)
#pragma unroll
        for (int r = 0; r < 4; ++r) {
          int m = m0 + rf * 16 + (lane >> 4) * 4 + r;
          int h = w * 64 + cf * 16 + (lane & 15);
          o[(size_t)m * DH + h] = f2bf(acc[rf][cf][r] + bvv[cf]);
        }
  } else {
    int bb = m0 >> 12;
    int sl = m0 & 4095;
#pragma unroll
    for (int rf = 0; rf < 4; ++rf)
#pragma unroll
      for (int cf = 0; cf < 4; ++cf) {
        int s = sl + rf * 16 + (lane >> 4) * 4;
        int h = w * 64 + cf * 16 + (lane & 15);
        ushort4v o;
        o.x = f2bf(acc[rf][cf][0] + bvv[cf]);
        o.y = f2bf(acc[rf][cf][1] + bvv[cf]);
        o.z = f2bf(acc[rf][cf][2] + bvv[cf]);
        o.w = f2bf(acc[rf][cf][3] + bvv[cf]);
        *(ushort4v*)(vtbf + ((size_t)(bb * DH + h)) * S_LEN + s) = o;
      }
  }
}

// ---------------------------------------------------------------------------
// Kernel 3: fused masked attention = r13's correctness-proven kernel with the
// kv-split/atomics removed (single block owns all 4096 kv; l local; direct
// out write). 256 blocks x 512 thr, 64 q rows, KVB=64, NT=64.
//   QK role:  kvs2 = w&1 (32-kv slice), qh2 = w>>1 (16 q rows)  [qreg 32 VGPR]
//   PV role:  qs = w>>2 (32 q rows),  hs = w&3 (64 h cols)
// K staged via gl2lds dbuf (2x32KB); V DIRECT global->regs in 2 phases
// (V_a top, V_b after QK) — consumed after BAR1, latency hidden; reg-loads
// auto-guarded by compiler dep-waits. BAR1 = lgkm-only (r13); BAR2 = vmcnt(8)
// (drains stageK only — the one op with no register consumer).
// P single 8KB, r13 chunk layout + row involution (HW-verified).
// Softmax without max (scores bounded; exp(0)=1 = reference fill-0).
// LDS: K 2x32KB | P 8KB | l 512B = 74240 B -> 2 blocks/CU.
// ---------------------------------------------------------------------------
__global__ void __launch_bounds__(512, 4)
attn_kernel(const unsigned short* __restrict__ qbf,
            const unsigned short* __restrict__ kbf,
            const unsigned short* __restrict__ vtbf,
            const int* __restrict__ mask,
            float* __restrict__ out) {
  const int tid  = threadIdx.x;
  const int lane = tid & 63;
  const int w    = tid >> 6;          // 0..7
  const int j    = lane & 15;
  const int g    = lane >> 4;

  const int kvs2 = w & 1;             // QK role: 32-kv slice
  const int qh2  = w >> 1;            // QK role: 16-q group
  const int qs   = w >> 2;            // PV role
  const int hs   = w & 3;

  // XCD-aware decode (blocks on one XCD share a batch -> K/V L2-resident)
  const int bx = blockIdx.x;
  const int x  = bx & 7;
  const int b  = x >> 1;
  const int qt = (bx >> 3) * 2 + (x & 1);
  const int m0 = qt * 64;

  __shared__ char sbuf[74240];
  // K: buf*32768 [0,65536) ; P: 65536 [8KB) ; lbuf: 73728 [64][2] f32
  float* lbuf = (float*)(sbuf + 73728);

  // ---- Q fragments (QK role): rows qh2*16 + j, 8 k-chunks  [32 VGPR]
  short8 qreg[8];
  {
    const unsigned short* qrow =
        qbf + ((size_t)(b * S_LEN + m0 + qh2 * 16 + j)) * DH + g * 8;
#pragma unroll
    for (int kc = 0; kc < 8; ++kc) qreg[kc] = *(const short8*)(qrow + kc * 32);
  }

  f32x4 zero = {0.f, 0.f, 0.f, 0.f};
  f32x4 acc[2][4];
#pragma unroll
  for (int a = 0; a < 2; ++a)
#pragma unroll
    for (int hf = 0; hf < 4; ++hf) acc[a][hf] = zero;
  float lrow[4] = {0.f, 0.f, 0.f, 0.f};

  // mask base (raw int32): q = m0 + qh2*16 + g*4 + r ; kv = t*64 + kvs2*32 +
  // kvf*16 + j
  const int* mb = mask + ((size_t)(b * S_LEN + m0 + qh2 * 16 + g * 4)) * S_LEN
                  + kvs2 * 32 + j;
  int mcur, mnext;

  // ---- K staging: 32 chunks of 1KB, 4 per wave, wave-uniform LDS dst
  auto stageK = [&](int t1, int bufbase) {
    const char* src = (const char*)kbf + ((size_t)(b * S_LEN + t1 * 64)) * 512;
    char* dst = sbuf + bufbase + w * 4096;
#pragma unroll
    for (int i = 0; i < 4; ++i) {
      int rid = w * 4 + i;            // ks = rid>>3 (16-kv group), kc = rid&7
      int ks  = rid >> 3;
      int kc  = rid & 7;
      gl2lds16(src + (size_t)(ks * 16 + j) * 512 + kc * 64 + g * 16, dst + i * 1024);
    }
  };

  // V direct base (PV role): row = b*DH + hs*64 + hf*16 + j
  const unsigned short* vbase =
      vtbf + ((size_t)(b * DH + hs * 64 + j)) * S_LEN + g * 8;

  // P write base (r13-verbatim, involution row' = r*4+g):
  // chunk = qh2*2 + kvs2 ; byte = kvf*512 + (j>>3)*256 + (r*4+g)*16 + (j&7)*2
  const int pwbase = 65536 + (qh2 * 2 + kvs2) * 1024 + (j >> 3) * 256 + (j & 7) * 2;

  auto loadmask = [&](int t1) -> int {
    int mm = 0;
#pragma unroll
    for (int kvf = 0; kvf < 2; ++kvf)
#pragma unroll
      for (int r = 0; r < 4; ++r)
        mm |= (mb[(size_t)r * S_LEN + t1 * 64 + kvf * 16] != 0) << (kvf * 4 + r);
    return mm;
  };

  // prologue
  stageK(0, 0);
  mcur = loadmask(0);
  __syncthreads();

  const int NT = S_LEN / 64;   // 64
  for (int t = 0; t < NT; ++t) {
    const int bufb = (t & 1) * 32768;

    // ---- V_a(t) -> regs (kc2=0); consumed after BAR1 (dep-wait automatic)
    short8 va[4];
    {
      const unsigned short* vt = vbase + t * 64;
#pragma unroll
      for (int hf = 0; hf < 4; ++hf)
        va[hf] = *(const short8*)(vt + (size_t)(hf * 16) * S_LEN);
    }
    cbar();

    if (t + 1 < NT) {
      stageK(t + 1, bufb ^ 32768);     // gl2lds: drained at BAR2
      cbar();
      mnext = loadmask(t + 1);
    } else {
      mnext = 0;
    }
    cbar();

    // ---- QK(t): 16 MFMA (16q x 32kv), 4 partial chains (r13-verbatim)
    const char* kb0 = sbuf + bufb + (kvs2 * 2) * 8192;
    const char* kb1 = kb0 + 8192;
    f32x4 sA0 = zero, sB0 = zero, sA1 = zero, sB1 = zero;
    __builtin_amdgcn_s_setprio(1);
#pragma unroll
    for (int kc = 0; kc < 8; kc += 2) {
      short8 k00 = *(const short8*)(kb0 + kc * 1024 + lane * 16);
      short8 k01 = *(const short8*)(kb0 + (kc + 1) * 1024 + lane * 16);
      short8 k10 = *(const short8*)(kb1 + kc * 1024 + lane * 16);
      short8 k11 = *(const short8*)(kb1 + (kc + 1) * 1024 + lane * 16);
      sA0 = __builtin_amdgcn_mfma_f32_16x16x32_bf16(qreg[kc], k00, sA0, 0, 0, 0);
      sA1 = __builtin_amdgcn_mfma_f32_16x16x32_bf16(qreg[kc], k10, sA1, 0, 0, 0);
      sB0 = __builtin_amdgcn_mfma_f32_16x16x32_bf16(qreg[kc + 1], k01, sB0, 0, 0, 0);
      sB1 = __builtin_amdgcn_mfma_f32_16x16x32_bf16(qreg[kc + 1], k11, sB1, 0, 0, 0);
    }
    __builtin_amdgcn_s_setprio(0);

    // ---- V_b(t) -> regs (kc2=1), hidden under softmax + BAR1 + PV-a
    short8 vb[4];
    {
      const unsigned short* vt = vbase + t * 64 + 32;
#pragma unroll
      for (int hf = 0; hf < 4; ++hf)
        vb[hf] = *(const short8*)(vt + (size_t)(hf * 16) * S_LEN);
    }

    // ---- softmax (no max): p = mask ? exp(s) : 1 ; write P (bf16)
#pragma unroll
    for (int kvf = 0; kvf < 2; ++kvf) {
      char* pw = sbuf + pwbase + kvf * 512;
#pragma unroll
      for (int r = 0; r < 4; ++r) {
        float sv = kvf ? (sA1[r] + sB1[r]) : (sA0[r] + sB0[r]);
        sv = ((mcur >> (kvf * 4 + r)) & 1) ? sv : 0.0f;
        float e = __expf(sv);
        lrow[r] += e;
        *(unsigned short*)(pw + (r * 4 + g) * 16) = f2bf(e);
      }
    }

    bar_lgkm();                        // BAR1: P visible; prefetch in flight

    // ---- PV(t): P from LDS (r13 layout), V from regs
    const char* pbase = sbuf + 65536 + qs * 4096;
    {
      short8 pf0 = *(const short8*)(pbase + lane * 16);           // qf2=0,kc2=0
      short8 pf1 = *(const short8*)(pbase + 2048 + lane * 16);    // qf2=1,kc2=0
      __builtin_amdgcn_s_setprio(1);
#pragma unroll
      for (int hf = 0; hf < 4; ++hf) {
        acc[0][hf] = __builtin_amdgcn_mfma_f32_16x16x32_bf16(pf0, va[hf], acc[0][hf], 0, 0, 0);
        acc[1][hf] = __builtin_amdgcn_mfma_f32_16x16x32_bf16(pf1, va[hf], acc[1][hf], 0, 0, 0);
      }
      short8 pf2 = *(const short8*)(pbase + 1024 + lane * 16);    // qf2=0,kc2=1
      short8 pf3 = *(const short8*)(pbase + 3072 + lane * 16);    // qf2=1,kc2=1
#pragma unroll
      for (int hf = 0; hf < 4; ++hf) {
        acc[0][hf] = __builtin_amdgcn_mfma_f32_16x16x32_bf16(pf2, vb[hf], acc[0][hf], 0, 0, 0);
        acc[1][hf] = __builtin_amdgcn_mfma_f32_16x16x32_bf16(pf3, vb[hf], acc[1][hf], 0, 0, 0);
      }
      __builtin_amdgcn_s_setprio(0);
    }

    mcur = mnext;
    // BAR2: stageK(t+1) drained (>=8 reg-loads younger); P reads complete.
    if (t + 1 < NT) bar_vm8(); else bar_vm0();
  }

  // ---- epilogue: l over 16 j-lanes, combine the 2 kv-slices via lbuf
#pragma unroll
  for (int r = 0; r < 4; ++r) {
#pragma unroll
    for (int off = 1; off < 16; off <<= 1)
      lrow[r] += __shfl_xor(lrow[r], off, 64);
  }
  if (j == 0) {
#pragma unroll
    for (int r = 0; r < 4; ++r)
      lbuf[(qh2 * 16 + g * 4 + r) * 2 + kvs2] = lrow[r];
  }
  __syncthreads();

#pragma unroll
  for (int qf2 = 0; qf2 < 2; ++qf2)
#pragma unroll
    for (int rr = 0; rr < 4; ++rr) {
      int qb = qs * 32 + qf2 * 16 + rr * 4 + g;   // physical q (involution undone)
      float linv = 1.0f / (lbuf[qb * 2] + lbuf[qb * 2 + 1]);
      float* orow = out + ((size_t)(b * S_LEN + m0 + qb)) * DH + hs * 64 + j;
#pragma unroll
      for (int hf = 0; hf < 4; ++hf)
        orow[hf * 16] = acc[qf2][hf][rr] * linv;
    }
}

// ---------------------------------------------------------------------------
extern "C" void kernel_launch(void* const* d_in, const int* in_sizes, int n_in,
                              void* d_out, int out_size, void* d_ws, size_t ws_size,
                              hipStream_t stream) {
  const float* xq = (const float*)d_in[0];
  const float* xk = (const float*)d_in[1];
  const float* xv = (const float*)d_in[2];
  const int* mask = (const int*)d_in[3];
  const float* wq = (const float*)d_in[4];
  const float* bq = (const float*)d_in[5];
  const float* wk = (const float*)d_in[6];
  const float* bk = (const float*)d_in[7];
  const float* wv = (const float*)d_in[8];
  const float* bv = (const float*)d_in[9];
  float* out = (float*)d_out;

  char* ws = (char*)d_ws;
  unsigned short* wbf  = (unsigned short*)(ws);                    // 1.5 MB
  unsigned short* qbf  = (unsigned short*)(ws + (2ull  << 20));    // 8 MB
  unsigned short* kbf  = (unsigned short*)(ws + (10ull << 20));    // 8 MB
  unsigned short* vtbf = (unsigned short*)(ws + (18ull << 20));    // 8 MB

  hipLaunchKernelGGL(wcvt_kernel, dim3(768), dim3(256), 0, stream, wq, wk, wv, wbf);
  hipLaunchKernelGGL(proj_kernel, dim3(256, 1, 3), dim3(256), 0, stream,
                     xq, xk, xv, wbf, bq, bk, bv, qbf, kbf, vtbf);
  hipLaunchKernelGGL(attn_kernel, dim3(256), dim3(512), 0, stream,
                     qbf, kbf, vtbf, mask, out);
}

// Round 16
// 315.723 us; speedup vs baseline: 2.1541x; 2.1541x over previous
//
#include <hip/hip_runtime.h>
#include <cstdint>
#include <cstddef>

#define S_LEN 4096
#define DVEC  1024
#define DH    256

typedef __attribute__((ext_vector_type(8))) short short8;
typedef __attribute__((ext_vector_type(4))) float f32x4;
typedef __attribute__((ext_vector_type(4))) unsigned short ushort4v;

__device__ __forceinline__ unsigned short f2bf(float f) {
  unsigned u = __builtin_bit_cast(unsigned, f);
  u += 0x7FFFu + ((u >> 16) & 1u);          // round-to-nearest-even
  return (unsigned short)(u >> 16);
}

__device__ __forceinline__ void gl2lds16(const void* g, void* lds) {
  __builtin_amdgcn_global_load_lds(
      (const __attribute__((address_space(1))) unsigned int*)g,
      (__attribute__((address_space(3))) unsigned int*)lds, 16, 0, 0);
}

__device__ __forceinline__ void cbar() { asm volatile("" ::: "memory"); }

// BAR1: LDS visibility only (P writes / QK reads). All register loads
// (V, mask) are auto-guarded by compiler dep-waits.
__device__ __forceinline__ void bar_lgkm() {
  asm volatile("s_waitcnt lgkmcnt(0)" ::: "memory");
  __builtin_amdgcn_s_barrier();
  asm volatile("" ::: "memory");
}
// BAR2: additionally drains stageK's gl2lds (the only op with no register
// consumer). >=12 reg-loads are issued after stageK (cbar-fenced), so
// vmcnt(8) strictly covers it; worst case also waits on 4 old mask loads.
__device__ __forceinline__ void bar_vm8() {
  asm volatile("s_waitcnt vmcnt(8) lgkmcnt(0)" ::: "memory");
  __builtin_amdgcn_s_barrier();
  asm volatile("" ::: "memory");
}
__device__ __forceinline__ void bar_vm0() {
  asm volatile("s_waitcnt vmcnt(0) lgkmcnt(0)" ::: "memory");
  __builtin_amdgcn_s_barrier();
  asm volatile("" ::: "memory");
}

// ---------------------------------------------------------------------------
// Kernel 1: weights f32 -> bf16 (wq pre-scaled by 1/sqrt(DH)=1/16).
// ---------------------------------------------------------------------------
__global__ void wcvt_kernel(const float* __restrict__ wq,
                            const float* __restrict__ wk,
                            const float* __restrict__ wv,
                            unsigned short* __restrict__ wbf) {
  int t   = blockIdx.x * 256 + threadIdx.x;
  int idx = t * 4;
  int m   = idx >> 18;
  int off = idx & 262143;
  const float* src = (m == 0) ? wq : (m == 1) ? wk : wv;
  float scale = (m == 0) ? 0.0625f : 1.0f;
  f32x4 v = *(const f32x4*)(src + off);
  ushort4v o;
  o.x = f2bf(v.x * scale);
  o.y = f2bf(v.y * scale);
  o.z = f2bf(v.z * scale);
  o.w = f2bf(v.w * scale);
  *(ushort4v*)(wbf + idx) = o;
}

// ---------------------------------------------------------------------------
// Kernel 2: projection GEMM (unchanged). C = x * W^T + b -> bf16; z==2 -> V^T.
// ---------------------------------------------------------------------------
__global__ void proj_kernel(const float* __restrict__ xq,
                            const float* __restrict__ xk,
                            const float* __restrict__ xv,
                            const unsigned short* __restrict__ wbf,
                            const float* __restrict__ bq,
                            const float* __restrict__ bk,
                            const float* __restrict__ bv,
                            unsigned short* __restrict__ qbf,
                            unsigned short* __restrict__ kbf,
                            unsigned short* __restrict__ vtbf) {
  const int tid  = threadIdx.x;
  const int lane = tid & 63;
  const int w    = tid >> 6;
  const int z    = blockIdx.z;
  const int m0   = blockIdx.x * 64;

  const float* x = (z == 0) ? xq : (z == 1) ? xk : xv;
  const unsigned short* wz = wbf + (size_t)z * (DH * DVEC);
  const float* bias = (z == 0) ? bq : (z == 1) ? bk : bv;
  const float bscale = (z == 0) ? 0.0625f : 1.0f;

  __shared__ float At[2][64 * 32];

  f32x4 zero = {0.f, 0.f, 0.f, 0.f};
  f32x4 acc[4][4];
#pragma unroll
  for (int i = 0; i < 4; ++i)
#pragma unroll
    for (int j = 0; j < 4; ++j) acc[i][j] = zero;

  auto stage = [&](int kt, int buf) {
    char* dstb = (char*)&At[buf][0] + w * 2048;
#pragma unroll
    for (int i = 0; i < 2; ++i) {
      int lin  = w * 2048 + i * 1024 + lane * 16;
      int row  = lin >> 7;
      int scol = (lin ^ ((row & 7) << 4)) & 127;
      gl2lds16((const char*)x + ((size_t)(m0 + row) * DVEC + kt * 32) * 4 + scol,
               dstb + i * 1024);
    }
  };

  stage(0, 0);
  __syncthreads();

  for (int kt = 0; kt < 32; ++kt) {
    const int buf = kt & 1;
    if (kt + 1 < 32) stage(kt + 1, buf ^ 1);

    short8 bfr[4];
#pragma unroll
    for (int cf = 0; cf < 4; ++cf) {
      int h = w * 64 + cf * 16 + (lane & 15);
      int d = kt * 32 + (lane >> 4) * 8;
      bfr[cf] = *(const short8*)(wz + (size_t)h * DVEC + d);
    }
    const char* ab = (const char*)&At[buf][0];
#pragma unroll
    for (int rf = 0; rf < 4; ++rf) {
      int row = rf * 16 + (lane & 15);
      int c0  = row * 128 + (lane >> 4) * 32;
      int sw  = (row & 7) << 4;
      f32x4 v0 = *(const f32x4*)(ab + (c0 ^ sw));
      f32x4 v1 = *(const f32x4*)(ab + ((c0 + 16) ^ sw));
      short8 af;
      af[0] = (short)f2bf(v0.x); af[1] = (short)f2bf(v0.y);
      af[2] = (short)f2bf(v0.z); af[3] = (short)f2bf(v0.w);
      af[4] = (short)f2bf(v1.x); af[5] = (short)f2bf(v1.y);
      af[6] = (short)f2bf(v1.z); af[7] = (short)f2bf(v1.w);
#pragma unroll
      for (int cf = 0; cf < 4; ++cf)
        acc[rf][cf] = __builtin_amdgcn_mfma_f32_16x16x32_bf16(af, bfr[cf], acc[rf][cf], 0, 0, 0);
    }
    __syncthreads();
  }

  float bvv[4];
#pragma unroll
  for (int cf = 0; cf < 4; ++cf)
    bvv[cf] = bias[w * 64 + cf * 16 + (lane & 15)] * bscale;

  if (z < 2) {
    unsigned short* o = (z == 0) ? qbf : kbf;
#pragma unroll
    for (int rf = 0; rf < 4; ++rf)
#pragma unroll
      for (int cf = 0; cf < 4; ++cf)
#pragma unroll
        for (int r = 0; r < 4; ++r) {
          int m = m0 + rf * 16 + (lane >> 4) * 4 + r;
          int h = w * 64 + cf * 16 + (lane & 15);
          o[(size_t)m * DH + h] = f2bf(acc[rf][cf][r] + bvv[cf]);
        }
  } else {
    int bb = m0 >> 12;
    int sl = m0 & 4095;
#pragma unroll
    for (int rf = 0; rf < 4; ++rf)
#pragma unroll
      for (int cf = 0; cf < 4; ++cf) {
        int s = sl + rf * 16 + (lane >> 4) * 4;
        int h = w * 64 + cf * 16 + (lane & 15);
        ushort4v o;
        o.x = f2bf(acc[rf][cf][0] + bvv[cf]);
        o.y = f2bf(acc[rf][cf][1] + bvv[cf]);
        o.z = f2bf(acc[rf][cf][2] + bvv[cf]);
        o.w = f2bf(acc[rf][cf][3] + bvv[cf]);
        *(ushort4v*)(vtbf + ((size_t)(bb * DH + h)) * S_LEN + s) = o;
      }
  }
}

// ---------------------------------------------------------------------------
// Kernel 3: fused masked attention — r15 VERBATIM except __launch_bounds__
// (512,2): r15's (512,4) demanded 8 waves/SIMD -> 64-VGPR cap -> ~750 MB of
// scratch-spill writes per dispatch (WRITE_SIZE counter). (512,2) caps at
// 128 VGPR (r12's proven regime), no spill; LDS 74240 still allows 2
// blocks/CU.
//   QK role:  kvs2 = w&1 (32-kv slice), qh2 = w>>1 (16 q rows)
//   PV role:  qs = w>>2 (32 q rows),  hs = w&3 (64 h cols)
// K staged via gl2lds dbuf (2x32KB); V DIRECT global->regs in 2 phases;
// BAR1 = lgkm-only; BAR2 = vmcnt(8). P single 8KB, r13 layout + involution.
// Softmax without max (scores bounded; exp(0)=1 = reference fill-0).
// ---------------------------------------------------------------------------
__global__ void __launch_bounds__(512, 2)
attn_kernel(const unsigned short* __restrict__ qbf,
            const unsigned short* __restrict__ kbf,
            const unsigned short* __restrict__ vtbf,
            const int* __restrict__ mask,
            float* __restrict__ out) {
  const int tid  = threadIdx.x;
  const int lane = tid & 63;
  const int w    = tid >> 6;          // 0..7
  const int j    = lane & 15;
  const int g    = lane >> 4;

  const int kvs2 = w & 1;             // QK role: 32-kv slice
  const int qh2  = w >> 1;            // QK role: 16-q group
  const int qs   = w >> 2;            // PV role
  const int hs   = w & 3;

  // XCD-aware decode (blocks on one XCD share a batch -> K/V L2-resident)
  const int bx = blockIdx.x;
  const int x  = bx & 7;
  const int b  = x >> 1;
  const int qt = (bx >> 3) * 2 + (x & 1);
  const int m0 = qt * 64;

  __shared__ char sbuf[74240];
  // K: buf*32768 [0,65536) ; P: 65536 [8KB) ; lbuf: 73728 [64][2] f32
  float* lbuf = (float*)(sbuf + 73728);

  // ---- Q fragments (QK role): rows qh2*16 + j, 8 k-chunks  [32 VGPR]
  short8 qreg[8];
  {
    const unsigned short* qrow =
        qbf + ((size_t)(b * S_LEN + m0 + qh2 * 16 + j)) * DH + g * 8;
#pragma unroll
    for (int kc = 0; kc < 8; ++kc) qreg[kc] = *(const short8*)(qrow + kc * 32);
  }

  f32x4 zero = {0.f, 0.f, 0.f, 0.f};
  f32x4 acc[2][4];
#pragma unroll
  for (int a = 0; a < 2; ++a)
#pragma unroll
    for (int hf = 0; hf < 4; ++hf) acc[a][hf] = zero;
  float lrow[4] = {0.f, 0.f, 0.f, 0.f};

  // mask base (raw int32): q = m0 + qh2*16 + g*4 + r ; kv = t*64 + kvs2*32 +
  // kvf*16 + j
  const int* mb = mask + ((size_t)(b * S_LEN + m0 + qh2 * 16 + g * 4)) * S_LEN
                  + kvs2 * 32 + j;
  int mcur, mnext;

  // ---- K staging: 32 chunks of 1KB, 4 per wave, wave-uniform LDS dst
  auto stageK = [&](int t1, int bufbase) {
    const char* src = (const char*)kbf + ((size_t)(b * S_LEN + t1 * 64)) * 512;
    char* dst = sbuf + bufbase + w * 4096;
#pragma unroll
    for (int i = 0; i < 4; ++i) {
      int rid = w * 4 + i;            // ks = rid>>3 (16-kv group), kc = rid&7
      int ks  = rid >> 3;
      int kc  = rid & 7;
      gl2lds16(src + (size_t)(ks * 16 + j) * 512 + kc * 64 + g * 16, dst + i * 1024);
    }
  };

  // V direct base (PV role): row = b*DH + hs*64 + hf*16 + j
  const unsigned short* vbase =
      vtbf + ((size_t)(b * DH + hs * 64 + j)) * S_LEN + g * 8;

  // P write base (involution row' = r*4+g):
  // chunk = qh2*2 + kvs2 ; byte = kvf*512 + (j>>3)*256 + (r*4+g)*16 + (j&7)*2
  const int pwbase = 65536 + (qh2 * 2 + kvs2) * 1024 + (j >> 3) * 256 + (j & 7) * 2;

  auto loadmask = [&](int t1) -> int {
    int mm = 0;
#pragma unroll
    for (int kvf = 0; kvf < 2; ++kvf)
#pragma unroll
      for (int r = 0; r < 4; ++r)
        mm |= (mb[(size_t)r * S_LEN + t1 * 64 + kvf * 16] != 0) << (kvf * 4 + r);
    return mm;
  };

  // prologue
  stageK(0, 0);
  mcur = loadmask(0);
  __syncthreads();

  const int NT = S_LEN / 64;   // 64
  for (int t = 0; t < NT; ++t) {
    const int bufb = (t & 1) * 32768;

    // ---- V_a(t) -> regs (kc2=0); consumed after BAR1 (dep-wait automatic)
    short8 va[4];
    {
      const unsigned short* vt = vbase + t * 64;
#pragma unroll
      for (int hf = 0; hf < 4; ++hf)
        va[hf] = *(const short8*)(vt + (size_t)(hf * 16) * S_LEN);
    }
    cbar();

    if (t + 1 < NT) {
      stageK(t + 1, bufb ^ 32768);     // gl2lds: drained at BAR2
      cbar();
      mnext = loadmask(t + 1);
    } else {
      mnext = 0;
    }
    cbar();

    // ---- QK(t): 16 MFMA (16q x 32kv), 4 partial chains
    const char* kb0 = sbuf + bufb + (kvs2 * 2) * 8192;
    const char* kb1 = kb0 + 8192;
    f32x4 sA0 = zero, sB0 = zero, sA1 = zero, sB1 = zero;
    __builtin_amdgcn_s_setprio(1);
#pragma unroll
    for (int kc = 0; kc < 8; kc += 2) {
      short8 k00 = *(const short8*)(kb0 + kc * 1024 + lane * 16);
      short8 k01 = *(const short8*)(kb0 + (kc + 1) * 1024 + lane * 16);
      short8 k10 = *(const short8*)(kb1 + kc * 1024 + lane * 16);
      short8 k11 = *(const short8*)(kb1 + (kc + 1) * 1024 + lane * 16);
      sA0 = __builtin_amdgcn_mfma_f32_16x16x32_bf16(qreg[kc], k00, sA0, 0, 0, 0);
      sA1 = __builtin_amdgcn_mfma_f32_16x16x32_bf16(qreg[kc], k10, sA1, 0, 0, 0);
      sB0 = __builtin_amdgcn_mfma_f32_16x16x32_bf16(qreg[kc + 1], k01, sB0, 0, 0, 0);
      sB1 = __builtin_amdgcn_mfma_f32_16x16x32_bf16(qreg[kc + 1], k11, sB1, 0, 0, 0);
    }
    __builtin_amdgcn_s_setprio(0);

    // ---- V_b(t) -> regs (kc2=1), hidden under softmax + BAR1 + PV-a
    short8 vb[4];
    {
      const unsigned short* vt = vbase + t * 64 + 32;
#pragma unroll
      for (int hf = 0; hf < 4; ++hf)
        vb[hf] = *(const short8*)(vt + (size_t)(hf * 16) * S_LEN);
    }

    // ---- softmax (no max): p = mask ? exp(s) : 1 ; write P (bf16)
#pragma unroll
    for (int kvf = 0; kvf < 2; ++kvf) {
      char* pw = sbuf + pwbase + kvf * 512;
#pragma unroll
      for (int r = 0; r < 4; ++r) {
        float sv = kvf ? (sA1[r] + sB1[r]) : (sA0[r] + sB0[r]);
        sv = ((mcur >> (kvf * 4 + r)) & 1) ? sv : 0.0f;
        float e = __expf(sv);
        lrow[r] += e;
        *(unsigned short*)(pw + (r * 4 + g) * 16) = f2bf(e);
      }
    }

    bar_lgkm();                        // BAR1: P visible; prefetch in flight

    // ---- PV(t): P from LDS, V from regs
    const char* pbase = sbuf + 65536 + qs * 4096;
    {
      short8 pf0 = *(const short8*)(pbase + lane * 16);           // qf2=0,kc2=0
      short8 pf1 = *(const short8*)(pbase + 2048 + lane * 16);    // qf2=1,kc2=0
      __builtin_amdgcn_s_setprio(1);
#pragma unroll
      for (int hf = 0; hf < 4; ++hf) {
        acc[0][hf] = __builtin_amdgcn_mfma_f32_16x16x32_bf16(pf0, va[hf], acc[0][hf], 0, 0, 0);
        acc[1][hf] = __builtin_amdgcn_mfma_f32_16x16x32_bf16(pf1, va[hf], acc[1][hf], 0, 0, 0);
      }
      short8 pf2 = *(const short8*)(pbase + 1024 + lane * 16);    // qf2=0,kc2=1
      short8 pf3 = *(const short8*)(pbase + 3072 + lane * 16);    // qf2=1,kc2=1
#pragma unroll
      for (int hf = 0; hf < 4; ++hf) {
        acc[0][hf] = __builtin_amdgcn_mfma_f32_16x16x32_bf16(pf2, vb[hf], acc[0][hf], 0, 0, 0);
        acc[1][hf] = __builtin_amdgcn_mfma_f32_16x16x32_bf16(pf3, vb[hf], acc[1][hf], 0, 0, 0);
      }
      __builtin_amdgcn_s_setprio(0);
    }

    mcur = mnext;
    // BAR2: stageK(t+1) drained (>=8 reg-loads younger); P reads complete.
    if (t + 1 < NT) bar_vm8(); else bar_vm0();
  }

  // ---- epilogue: l over 16 j-lanes, combine the 2 kv-slices via lbuf
#pragma unroll
  for (int r = 0; r < 4; ++r) {
#pragma unroll
    for (int off = 1; off < 16; off <<= 1)
      lrow[r] += __shfl_xor(lrow[r], off, 64);
  }
  if (j == 0) {
#pragma unroll
    for (int r = 0; r < 4; ++r)
      lbuf[(qh2 * 16 + g * 4 + r) * 2 + kvs2] = lrow[r];
  }
  __syncthreads();

#pragma unroll
  for (int qf2 = 0; qf2 < 2; ++qf2)
#pragma unroll
    for (int rr = 0; rr < 4; ++rr) {
      int qb = qs * 32 + qf2 * 16 + rr * 4 + g;   // physical q (involution undone)
      float linv = 1.0f / (lbuf[qb * 2] + lbuf[qb * 2 + 1]);
      float* orow = out + ((size_t)(b * S_LEN + m0 + qb)) * DH + hs * 64 + j;
#pragma unroll
      for (int hf = 0; hf < 4; ++hf)
        orow[hf * 16] = acc[qf2][hf][rr] * linv;
    }
}

// ---------------------------------------------------------------------------
extern "C" void kernel_launch(void* const* d_in, const int* in_sizes, int n_in,
                              void* d_out, int out_size, void* d_ws, size_t ws_size,
                              hipStream_t stream) {
  const float* xq = (const float*)d_in[0];
  const float* xk = (const float*)d_in[1];
  const float* xv = (const float*)d_in[2];
  const int* mask = (const int*)d_in[3];
  const float* wq = (const float*)d_in[4];
  const float* bq = (const float*)d_in[5];
  const float* wk = (const float*)d_in[6];
  const float* bk = (const float*)d_in[7];
  const float* wv = (const float*)d_in[8];
  const float* bv = (const float*)d_in[9];
  float* out = (float*)d_out;

  char* ws = (char*)d_ws;
  unsigned short* wbf  = (unsigned short*)(ws);                    // 1.5 MB
  unsigned short* qbf  = (unsigned short*)(ws + (2ull  << 20));    // 8 MB
  unsigned short* kbf  = (unsigned short*)(ws + (10ull << 20));    // 8 MB
  unsigned short* vtbf = (unsigned short*)(ws + (18ull << 20));    // 8 MB

  hipLaunchKernelGGL(wcvt_kernel, dim3(768), dim3(256), 0, stream, wq, wk, wv, wbf);
  hipLaunchKernelGGL(proj_kernel, dim3(256, 1, 3), dim3(256), 0, stream,
                     xq, xk, xv, wbf, bq, bk, bv, qbf, kbf, vtbf);
  hipLaunchKernelGGL(attn_kernel, dim3(256), dim3(512), 0, stream,
                     qbf, kbf, vtbf, mask, out);
}